// Round 1
// baseline (2055.952 us; speedup 1.0000x reference)
//
#include <hip/hip_runtime.h>
#include <math.h>

#define EPS 1e-6f

constexpr int BSZ = 16;    // batch * S
constexpr int DD  = 512;   // channels / S
constexpr int NN  = 4096;  // H*W
constexpr int RR  = 64;
constexpr int STEPS = 7;
constexpr int NSPLIT = 8;

__device__ __forceinline__ void fma4(float4& a, float s, const float4& b) {
  a.x += s * b.x; a.y += s * b.y; a.z += s * b.z; a.w += s * b.w;
}

// out[r][k] = sum_{rows in split} M[row][r] * M[row][k]
__global__ void __launch_bounds__(256) gram_kernel(const float* __restrict__ M,
                                                   float* __restrict__ out,
                                                   int rowsPerSplit,
                                                   unsigned long long batchStride) {
  const float* Mp = M + (size_t)blockIdx.y * batchStride +
                    (size_t)blockIdx.x * rowsPerSplit * RR;
  float* op = out + ((size_t)blockIdx.x * gridDim.y + blockIdx.y) * (RR * RR);
  __shared__ float sm[64][64];
  const int k  = threadIdx.x & 63;
  const int r0 = (threadIdx.x >> 6) << 4;
  float4 acc[4];
  acc[0] = acc[1] = acc[2] = acc[3] = make_float4(0.f, 0.f, 0.f, 0.f);
  for (int c0 = 0; c0 < rowsPerSplit; c0 += 64) {
    for (int s = threadIdx.x; s < 1024; s += 256) {
      const int row = s >> 4, c4 = (s & 15) << 2;
      *(float4*)&sm[row][c4] = *(const float4*)&Mp[(size_t)(c0 + row) * RR + c4];
    }
    __syncthreads();
    #pragma unroll 4
    for (int row = 0; row < 64; ++row) {
      const float mk = sm[row][k];
      const float4 a0 = *(const float4*)&sm[row][r0];
      const float4 a1 = *(const float4*)&sm[row][r0 + 4];
      const float4 a2 = *(const float4*)&sm[row][r0 + 8];
      const float4 a3 = *(const float4*)&sm[row][r0 + 12];
      fma4(acc[0], mk, a0); fma4(acc[1], mk, a1);
      fma4(acc[2], mk, a2); fma4(acc[3], mk, a3);
    }
    __syncthreads();
  }
  #pragma unroll
  for (int i = 0; i < 4; ++i) {
    op[(size_t)(r0 + i * 4 + 0) * RR + k] = acc[i].x;
    op[(size_t)(r0 + i * 4 + 1) * RR + k] = acc[i].y;
    op[(size_t)(r0 + i * 4 + 2) * RR + k] = acc[i].z;
    op[(size_t)(r0 + i * 4 + 3) * RR + k] = acc[i].w;
  }
}

// MODE 0: coef = softmax(x^T bases); MODE 1: coef *= (x^T bases)/(coef@BtB + eps)
template <int MODE>
__global__ void __launch_bounds__(256) coef_kernel(const float* __restrict__ X,
                                                   const float* __restrict__ Bw,
                                                   const float* __restrict__ btb,
                                                   float* __restrict__ coef) {
  const int b  = blockIdx.y;
  const int n0 = blockIdx.x << 6;
  const float* Xp = X + (size_t)b * DD * NN;
  const float* Bp = Bw + (size_t)b * DD * RR;

  __shared__ float xs[64][68];
  __shared__ float bs[64][64];

  const int tx = threadIdx.x & 15;   // r = tx*4 + j
  const int ty = threadIdx.x >> 4;   // n = ty*4 + i

  float4 acc[4];
  acc[0] = acc[1] = acc[2] = acc[3] = make_float4(0.f, 0.f, 0.f, 0.f);

  for (int d0 = 0; d0 < DD; d0 += 64) {
    for (int s = threadIdx.x; s < 1024; s += 256) {
      const int dd = s >> 4, c4 = (s & 15) << 2;
      *(float4*)&xs[dd][c4] = *(const float4*)&Xp[(size_t)(d0 + dd) * NN + n0 + c4];
    }
    for (int s = threadIdx.x; s < 1024; s += 256) {
      const int dd = s >> 4, c4 = (s & 15) << 2;
      *(float4*)&bs[dd][c4] = *(const float4*)&Bp[(size_t)(d0 + dd) * RR + c4];
    }
    __syncthreads();
    #pragma unroll 8
    for (int dd = 0; dd < 64; ++dd) {
      const float4 xv = *(const float4*)&xs[dd][ty << 2];
      const float4 bv = *(const float4*)&bs[dd][tx << 2];
      fma4(acc[0], xv.x, bv); fma4(acc[1], xv.y, bv);
      fma4(acc[2], xv.z, bv); fma4(acc[3], xv.w, bv);
    }
    __syncthreads();
  }

  if (MODE == 0) {
    #pragma unroll
    for (int i = 0; i < 4; ++i)
      *(float4*)&xs[(ty << 2) + i][tx << 2] = acc[i];
    __syncthreads();
    if (threadIdx.x < 64) {
      const int n = threadIdx.x;
      float m = -1e30f;
      for (int r = 0; r < 64; ++r) m = fmaxf(m, xs[n][r]);
      float ssum = 0.f;
      for (int r = 0; r < 64; ++r) {
        const float e = __expf(xs[n][r] - m);
        xs[n][r] = e; ssum += e;
      }
      const float inv = 1.f / ssum;
      float* cp = coef + ((size_t)b * NN + n0 + n) * RR;
      for (int r = 0; r < 64; ++r) cp[r] = xs[n][r] * inv;
    }
  } else {
    // stage old coef tile and BtB
    for (int s = threadIdx.x; s < 1024; s += 256) {
      const int nn = s >> 4, c4 = (s & 15) << 2;
      *(float4*)&xs[nn][c4] = *(const float4*)&coef[((size_t)b * NN + n0 + nn) * RR + c4];
    }
    for (int s = threadIdx.x; s < 1024; s += 256) {
      const int rr = s >> 4, c4 = (s & 15) << 2;
      *(float4*)&bs[rr][c4] = *(const float4*)&btb[(size_t)b * RR * RR + (size_t)rr * RR + c4];
    }
    __syncthreads();
    float4 dn[4];
    dn[0] = dn[1] = dn[2] = dn[3] = make_float4(0.f, 0.f, 0.f, 0.f);
    #pragma unroll 4
    for (int kk = 0; kk < 64; kk += 4) {
      float4 cv[4], bv[4];
      #pragma unroll
      for (int i = 0; i < 4; ++i) cv[i] = *(const float4*)&xs[(ty << 2) + i][kk];
      #pragma unroll
      for (int u = 0; u < 4; ++u) bv[u] = *(const float4*)&bs[kk + u][tx << 2];
      #pragma unroll
      for (int i = 0; i < 4; ++i) {
        fma4(dn[i], cv[i].x, bv[0]); fma4(dn[i], cv[i].y, bv[1]);
        fma4(dn[i], cv[i].z, bv[2]); fma4(dn[i], cv[i].w, bv[3]);
      }
    }
    #pragma unroll
    for (int i = 0; i < 4; ++i) {
      const float4 cold = *(const float4*)&xs[(ty << 2) + i][tx << 2];
      float4 o;
      o.x = cold.x * acc[i].x / (dn[i].x + EPS);
      o.y = cold.y * acc[i].y / (dn[i].y + EPS);
      o.z = cold.z * acc[i].z / (dn[i].z + EPS);
      o.w = cold.w * acc[i].w / (dn[i].w + EPS);
      *(float4*)&coef[((size_t)b * NN + n0 + (ty << 2) + i) * RR + (tx << 2)] = o;
    }
  }
}

// n2p[split][b][d][r] = sum_{n in split} x[d][n] * coef[n][r]
__global__ void __launch_bounds__(256) numer2_kernel(const float* __restrict__ X,
                                                     const float* __restrict__ coef,
                                                     float* __restrict__ n2p) {
  const int d0    = blockIdx.x << 6;
  const int split = blockIdx.y;
  const int b     = blockIdx.z;
  const float* Xp = X + (size_t)b * DD * NN;
  const float* Cp = coef + (size_t)b * NN * RR;
  __shared__ float xs[64][68];
  __shared__ float cs[64][64];
  const int tx = threadIdx.x & 15;
  const int ty = threadIdx.x >> 4;
  float4 acc[4];
  acc[0] = acc[1] = acc[2] = acc[3] = make_float4(0.f, 0.f, 0.f, 0.f);
  const int nbeg = split * (NN / NSPLIT);
  for (int nc = 0; nc < NN / NSPLIT; nc += 64) {
    const int nb = nbeg + nc;
    for (int s = threadIdx.x; s < 1024; s += 256) {
      const int dd = s >> 4, c4 = (s & 15) << 2;
      *(float4*)&xs[dd][c4] = *(const float4*)&Xp[(size_t)(d0 + dd) * NN + nb + c4];
    }
    for (int s = threadIdx.x; s < 1024; s += 256) {
      const int nn = s >> 4, c4 = (s & 15) << 2;
      *(float4*)&cs[nn][c4] = *(const float4*)&Cp[(size_t)(nb + nn) * RR + c4];
    }
    __syncthreads();
    #pragma unroll 4
    for (int nn = 0; nn < 64; nn += 4) {
      float4 xv[4], cv[4];
      #pragma unroll
      for (int i = 0; i < 4; ++i) xv[i] = *(const float4*)&xs[(ty << 2) + i][nn];
      #pragma unroll
      for (int u = 0; u < 4; ++u) cv[u] = *(const float4*)&cs[nn + u][tx << 2];
      #pragma unroll
      for (int i = 0; i < 4; ++i) {
        fma4(acc[i], xv[i].x, cv[0]); fma4(acc[i], xv[i].y, cv[1]);
        fma4(acc[i], xv[i].z, cv[2]); fma4(acc[i], xv[i].w, cv[3]);
      }
    }
    __syncthreads();
  }
  float* op = n2p + (((size_t)split * BSZ + b) * DD + d0) * RR;
  #pragma unroll
  for (int i = 0; i < 4; ++i)
    *(float4*)&op[(size_t)((ty << 2) + i) * RR + (tx << 2)] = acc[i];
}

// bases[d][r] *= sum_sp n2p / (sum_r bases_old[d][r]*CtC[r][c] + eps)
__global__ void __launch_bounds__(256) bupdate_kernel(float* __restrict__ Bw,
                                                      const float* __restrict__ n2p,
                                                      const float* __restrict__ ctcp) {
  const int d0 = blockIdx.x << 6;
  const int b  = blockIdx.y;
  __shared__ float bo[64][68];
  __shared__ float ct[64][64];
  const int tx = threadIdx.x & 15;
  const int ty = threadIdx.x >> 4;
  for (int s = threadIdx.x; s < 1024; s += 256) {
    const int dd = s >> 4, c4 = (s & 15) << 2;
    *(float4*)&bo[dd][c4] = *(const float4*)&Bw[((size_t)b * DD + d0 + dd) * RR + c4];
  }
  for (int s = threadIdx.x; s < 1024; s += 256) {
    const int rr = s >> 4, c4 = (s & 15) << 2;
    float4 v = make_float4(0.f, 0.f, 0.f, 0.f);
    #pragma unroll
    for (int sp = 0; sp < NSPLIT; ++sp) {
      const float4 t = *(const float4*)&ctcp[((size_t)sp * BSZ + b) * (RR * RR) +
                                             (size_t)rr * RR + c4];
      v.x += t.x; v.y += t.y; v.z += t.z; v.w += t.w;
    }
    *(float4*)&ct[rr][c4] = v;
  }
  __syncthreads();
  float4 dn[4];
  dn[0] = dn[1] = dn[2] = dn[3] = make_float4(0.f, 0.f, 0.f, 0.f);
  #pragma unroll 4
  for (int kk = 0; kk < 64; kk += 4) {
    float4 bv[4], cv[4];
    #pragma unroll
    for (int i = 0; i < 4; ++i) bv[i] = *(const float4*)&bo[(ty << 2) + i][kk];
    #pragma unroll
    for (int u = 0; u < 4; ++u) cv[u] = *(const float4*)&ct[kk + u][tx << 2];
    #pragma unroll
    for (int i = 0; i < 4; ++i) {
      fma4(dn[i], bv[i].x, cv[0]); fma4(dn[i], bv[i].y, cv[1]);
      fma4(dn[i], bv[i].z, cv[2]); fma4(dn[i], bv[i].w, cv[3]);
    }
  }
  const size_t sstride = (size_t)BSZ * DD * RR;
  #pragma unroll
  for (int i = 0; i < 4; ++i) {
    const size_t rowoff = ((size_t)b * DD + d0 + (ty << 2) + i) * RR + (tx << 2);
    float4 ns = make_float4(0.f, 0.f, 0.f, 0.f);
    #pragma unroll
    for (int sp = 0; sp < NSPLIT; ++sp) {
      const float4 t = *(const float4*)&n2p[sp * sstride + rowoff];
      ns.x += t.x; ns.y += t.y; ns.z += t.z; ns.w += t.w;
    }
    const float4 bold = *(const float4*)&bo[(ty << 2) + i][tx << 2];
    float4 o;
    o.x = bold.x * ns.x / (dn[i].x + EPS);
    o.y = bold.y * ns.y / (dn[i].y + EPS);
    o.z = bold.z * ns.z / (dn[i].z + EPS);
    o.w = bold.w * ns.w / (dn[i].w + EPS);
    *(float4*)&Bw[rowoff] = o;
  }
}

// out[d][n] = sum_r bases[d][r] * coef[n][r]
__global__ void __launch_bounds__(256) out_kernel(const float* __restrict__ Bw,
                                                  const float* __restrict__ coef,
                                                  float* __restrict__ out) {
  const int n0 = blockIdx.x << 6;
  const int d0 = blockIdx.y << 6;
  const int b  = blockIdx.z;
  __shared__ float bsm[64][68];
  __shared__ float cs[64 * 64];  // XOR-swizzled [n][r]
  const int tx = threadIdx.x & 15;  // n = tx*4 + j
  const int ty = threadIdx.x >> 4;  // d = ty*4 + i
  for (int s = threadIdx.x; s < 1024; s += 256) {
    const int dd = s >> 4, c4 = (s & 15) << 2;
    *(float4*)&bsm[dd][c4] = *(const float4*)&Bw[((size_t)b * DD + d0 + dd) * RR + c4];
  }
  for (int s = threadIdx.x; s < 1024; s += 256) {
    const int nn = s >> 4, c = s & 15;
    const int csw = c ^ ((nn >> 2) & 7);
    *(float4*)&cs[nn * 64 + (csw << 2)] =
        *(const float4*)&coef[((size_t)b * NN + n0 + nn) * RR + (c << 2)];
  }
  __syncthreads();
  float acc[4][4] = {};
  #pragma unroll
  for (int r = 0; r < 64; r += 4) {
    float4 bv[4], cv[4];
    #pragma unroll
    for (int i = 0; i < 4; ++i) bv[i] = *(const float4*)&bsm[(ty << 2) + i][r];
    #pragma unroll
    for (int j = 0; j < 4; ++j) {
      const int nj  = (tx << 2) + j;
      const int csw = (r >> 2) ^ ((nj >> 2) & 7);
      cv[j] = *(const float4*)&cs[nj * 64 + (csw << 2)];
    }
    #pragma unroll
    for (int i = 0; i < 4; ++i) {
      #pragma unroll
      for (int j = 0; j < 4; ++j)
        acc[i][j] += bv[i].x * cv[j].x + bv[i].y * cv[j].y +
                     bv[i].z * cv[j].z + bv[i].w * cv[j].w;
    }
  }
  #pragma unroll
  for (int i = 0; i < 4; ++i) {
    const float4 o = make_float4(acc[i][0], acc[i][1], acc[i][2], acc[i][3]);
    *(float4*)&out[((size_t)b * DD + d0 + (ty << 2) + i) * NN + n0 + (tx << 2)] = o;
  }
}

extern "C" void kernel_launch(void* const* d_in, const int* in_sizes, int n_in,
                              void* d_out, int out_size, void* d_ws, size_t ws_size,
                              hipStream_t stream) {
  const float* x        = (const float*)d_in[0];
  const float* bases_in = (const float*)d_in[1];
  float* out = (float*)d_out;
  float* ws  = (float*)d_ws;

  float* coef    = ws;                                     // BSZ*NN*RR
  float* bases_w = coef + (size_t)BSZ * NN * RR;           // BSZ*DD*RR
  float* btb     = bases_w + (size_t)BSZ * DD * RR;        // BSZ*RR*RR
  float* ctcp    = btb + (size_t)BSZ * RR * RR;            // NSPLIT*BSZ*RR*RR
  float* n2p     = ctcp + (size_t)NSPLIT * BSZ * RR * RR;  // NSPLIT*BSZ*DD*RR

  hipMemcpyAsync(bases_w, bases_in, sizeof(float) * BSZ * DD * RR,
                 hipMemcpyDeviceToDevice, stream);

  const dim3 blk(256);
  coef_kernel<0><<<dim3(NN / 64, BSZ), blk, 0, stream>>>(x, bases_w, nullptr, coef);
  for (int it = 0; it < STEPS; ++it) {
    gram_kernel<<<dim3(1, BSZ), blk, 0, stream>>>(bases_w, btb, DD, (size_t)DD * RR);
    coef_kernel<1><<<dim3(NN / 64, BSZ), blk, 0, stream>>>(x, bases_w, btb, coef);
    numer2_kernel<<<dim3(DD / 64, NSPLIT, BSZ), blk, 0, stream>>>(x, coef, n2p);
    gram_kernel<<<dim3(NSPLIT, BSZ), blk, 0, stream>>>(coef, ctcp, NN / NSPLIT,
                                                       (size_t)NN * RR);
    bupdate_kernel<<<dim3(DD / 64, BSZ), blk, 0, stream>>>(bases_w, n2p, ctcp);
  }
  gram_kernel<<<dim3(1, BSZ), blk, 0, stream>>>(bases_w, btb, DD, (size_t)DD * RR);
  coef_kernel<1><<<dim3(NN / 64, BSZ), blk, 0, stream>>>(x, bases_w, btb, coef);
  out_kernel<<<dim3(NN / 64, DD / 64, BSZ), blk, 0, stream>>>(bases_w, coef, out);
}